// Round 14
// baseline (164.984 us; speedup 1.0000x reference)
//
#include <hip/hip_runtime.h>
#include <math.h>

#define DIMX 384
#define NHEAD 6
#define DHEAD 64
#define HW 3136   // 56*56
#define LKV 784   // 28*28
#define NGDX 128
#define NGRP 24   // B*3

typedef __bf16 bf16_t;
typedef __bf16 bf16x4 __attribute__((ext_vector_type(4)));
typedef __bf16 bf16x8 __attribute__((ext_vector_type(8)));
typedef float  f32x4  __attribute__((ext_vector_type(4)));

typedef unsigned int u32_g __attribute__((address_space(1)));
typedef unsigned int u32_l __attribute__((address_space(3)));

static __device__ __forceinline__ f32x4 mfma16(bf16x8 a, bf16x8 b, f32x4 c) {
  return __builtin_amdgcn_mfma_f32_16x16x32_bf16(a, b, c, 0, 0, 0);
}
// async global->LDS, 16B per lane; LDS dest = wave-uniform base + lane*16
static __device__ __forceinline__ void gload16(const void* g, void* l) {
  __builtin_amdgcn_global_load_lds((const u32_g*)g, (u32_l*)l, 16, 0, 0);
}

// convert the three weight matrices into one bf16 arena
__global__ __launch_bounds__(256) void cvt_w3(
    const float* __restrict__ qw, const float* __restrict__ kvw,
    const float* __restrict__ pw, bf16_t* __restrict__ dst)
{
  const int i = blockIdx.x * 256 + threadIdx.x;
  if (i >= 147456) return;
  const int e = i * 4;
  const float* src;
  int off;
  if (e < 147456)      { src = qw;  off = e; }
  else if (e < 442368) { src = kvw; off = e - 147456; }
  else                 { src = pw;  off = e - 442368; }
  const float4 v = *(const float4*)(src + off);
  bf16x4 o;
  o[0] = (bf16_t)v.x; o[1] = (bf16_t)v.y; o[2] = (bf16_t)v.z; o[3] = (bf16_t)v.w;
  *(bf16x4*)(dst + e) = o;
}

// ---------------------------------------------------------------------------
// Fused q-projection: reads x fp32 (b,c,p) DIRECTLY (no xt_cvt pass).
// A (weights) via gload16 + swizzled reads; B via convert+transpose scatter.
// out qbuf bf16 [b][o][p]. 1-D grid 2352 with XCD mapping blk=y*392+(b*49+x).
// ---------------------------------------------------------------------------
__global__ __launch_bounds__(256) void gemm_q(
    const bf16_t* __restrict__ W, const float* __restrict__ x,
    bf16_t* __restrict__ outq)
{
  const int C = DIMX, P = HW, O = DIMX;
  const int blk = blockIdx.x;
  const int y   = blk / 392;
  const int xb  = blk % 392;
  const int b   = xb / 49;
  const int o0  = y * 64;
  const int p0  = (xb % 49) * 64;
  __shared__ __align__(16) char smemA[8192];     // A 64x64 swizzled
  __shared__ __align__(16) bf16_t Bs[64][72];    // [p][c]
  const int tid = threadIdx.x;
  const int w = tid >> 6, lane = tid & 63, l15 = lane & 15, g = lane >> 4;
  const int lrow = lane >> 3;
  const int j    = lane & 7;

  const bf16_t* gA = W + (size_t)(o0 + w * 16 + lrow) * C + (j ^ lrow) * 8;

  f32x4 acc[4];
#pragma unroll
  for (int n = 0; n < 4; ++n) { acc[n][0]=0.f; acc[n][1]=0.f; acc[n][2]=0.f; acc[n][3]=0.f; }

  for (int c0 = 0; c0 < C; c0 += 64) {
    gload16(gA + c0,         smemA + w * 2048);
    gload16(gA + c0 + 8 * C, smemA + w * 2048 + 1024);
    // B: x[b][c0+c][p0+pp..pp+15] -> cvt bf16 -> Bs[pp..][c]
    {
      const int c = tid >> 2, pp = (tid & 3) * 16;
      const float* src = x + ((size_t)b * C + c0 + c) * HW + p0 + pp;
#pragma unroll
      for (int q4 = 0; q4 < 4; ++q4) {
        const float4 v = *(const float4*)(src + q4 * 4);
        Bs[pp + q4 * 4 + 0][c] = (bf16_t)v.x;
        Bs[pp + q4 * 4 + 1][c] = (bf16_t)v.y;
        Bs[pp + q4 * 4 + 2][c] = (bf16_t)v.z;
        Bs[pp + q4 * 4 + 3][c] = (bf16_t)v.w;
      }
    }
    __syncthreads();
#pragma unroll
    for (int ks = 0; ks < 2; ++ks) {
      const int cx = (ks * 64 + g * 16) ^ ((l15 & 7) << 4);
      const bf16x8 af = *(const bf16x8*)(smemA + (w * 16 + l15) * 128 + cx);
#pragma unroll
      for (int n = 0; n < 4; ++n) {
        const bf16x8 bfr = *(const bf16x8*)&Bs[n * 16 + l15][ks * 32 + g * 8];
        acc[n] = mfma16(af, bfr, acc[n]);
      }
    }
    __syncthreads();
  }

#pragma unroll
  for (int n = 0; n < 4; ++n) {
    const int p = p0 + n * 16 + l15;
#pragma unroll
    for (int r = 0; r < 4; ++r) {
      const int o = o0 + w * 16 + g * 4 + r;
      outq[((size_t)b * O + o) * P + p] = (bf16_t)acc[n][r];
    }
  }
}

// ---------------------------------------------------------------------------
// Fast GEMM for out-proj. Double-buffered global_load_lds staging,
// 1 barrier per K-step; XOR-swizzled reads. 1-D grid 2352 XCD mapping.
// ---------------------------------------------------------------------------
__global__ __launch_bounds__(256) void gemm_qo(
    const bf16_t* __restrict__ W, const bf16_t* __restrict__ in,
    const float* __restrict__ bias, float* __restrict__ out,
    int C, int P, int O)
{
  const int blk = blockIdx.x;
  const int y   = blk / 392;
  const int xb  = blk % 392;
  const int b   = xb / 49;
  const int o0  = y * 64;
  const int p0  = (xb % 49) * 64;
  __shared__ __align__(16) char smem[32768];
  const int tid = threadIdx.x;
  const int w = tid >> 6, lane = tid & 63, l15 = lane & 15, g = lane >> 4;
  const int lrow = lane >> 3;
  const int j    = lane & 7;

  const bf16_t* gA = W + (size_t)(o0 + w * 16 + lrow) * C + (j ^ lrow) * 8;
  const bf16_t* gB = in + ((size_t)b * P + p0 + w * 16 + lrow) * C + (j ^ lrow) * 8;

  f32x4 acc[4];
#pragma unroll
  for (int n = 0; n < 4; ++n) { acc[n][0]=0.f; acc[n][1]=0.f; acc[n][2]=0.f; acc[n][3]=0.f; }

  gload16(gA,         smem + w * 2048);
  gload16(gA + 8 * C, smem + w * 2048 + 1024);
  gload16(gB,         smem + 8192 + w * 2048);
  gload16(gB + 8 * C, smem + 8192 + w * 2048 + 1024);

  const int NK = C >> 6;
  for (int it = 0; it < NK; ++it) {
    const int buf = (it & 1) * 16384;
    __syncthreads();
    if (it + 1 < NK) {
      const int c1 = (it + 1) * 64;
      const int nb = ((it + 1) & 1) * 16384;
      gload16(gA + c1,         smem + nb + w * 2048);
      gload16(gA + c1 + 8 * C, smem + nb + w * 2048 + 1024);
      gload16(gB + c1,         smem + nb + 8192 + w * 2048);
      gload16(gB + c1 + 8 * C, smem + nb + 8192 + w * 2048 + 1024);
    }
#pragma unroll
    for (int ks = 0; ks < 2; ++ks) {
      const int cx = (ks * 64 + g * 16) ^ ((l15 & 7) << 4);
      const bf16x8 af = *(const bf16x8*)(smem + buf + (w * 16 + l15) * 128 + cx);
#pragma unroll
      for (int n = 0; n < 4; ++n) {
        const bf16x8 bfr = *(const bf16x8*)(smem + buf + 8192 + (n * 16 + l15) * 128 + cx);
        acc[n] = mfma16(af, bfr, acc[n]);
      }
    }
  }

  float badd[4];
#pragma unroll
  for (int r = 0; r < 4; ++r) badd[r] = bias[o0 + w * 16 + g * 4 + r];
#pragma unroll
  for (int n = 0; n < 4; ++n) {
    const int p = p0 + n * 16 + l15;
#pragma unroll
    for (int r = 0; r < 4; ++r) {
      const int o = o0 + w * 16 + g * 4 + r;
      out[((size_t)b * O + o) * P + p] = acc[n][r] + badd[r];
    }
  }
}

// ---------------------------------------------------------------------------
// bf16 MFMA GEMM (kv projection): in (b,c,p) transpose-scatter staging.
// Epilogue: o<384 -> K transposed [b,h,l,d]; o>=384 -> V [b,c,l].
// ---------------------------------------------------------------------------
__global__ __launch_bounds__(256) void gemm_kv(
    const bf16_t* __restrict__ W, const bf16_t* __restrict__ in,
    bf16_t* __restrict__ ktb, bf16_t* __restrict__ vtb, int C, int P, int O)
{
  const int b  = blockIdx.z;
  const int o0 = blockIdx.y * 64;
  const int p0 = blockIdx.x * 64;
  __shared__ __align__(16) bf16_t As[64][72];
  __shared__ __align__(16) bf16_t Bs[64][72];
  const int tid = threadIdx.x;
  const int w = tid >> 6, lane = tid & 63, l15 = lane & 15, g = lane >> 4;

  f32x4 acc[4];
#pragma unroll
  for (int n = 0; n < 4; ++n) { acc[n][0]=0.f; acc[n][1]=0.f; acc[n][2]=0.f; acc[n][3]=0.f; }

  for (int c0 = 0; c0 < C; c0 += 64) {
    {
      const int o = tid >> 2, cc = (tid & 3) * 16;
      const bf16_t* src = W + (size_t)(o0 + o) * C + c0 + cc;
      *(bf16x8*)&As[o][cc]     = *(const bf16x8*)src;
      *(bf16x8*)&As[o][cc + 8] = *(const bf16x8*)(src + 8);
    }
    {
      const int c = tid >> 2, pp = (tid & 3) * 16;
      const bf16_t* src = in + ((size_t)b * C + c0 + c) * P + p0 + pp;
#pragma unroll
      for (int jj = 0; jj < 2; ++jj) {
        bf16x8 v;
        if (p0 + pp + jj * 8 + 8 <= P) v = *(const bf16x8*)(src + jj * 8);
        else {
#pragma unroll
          for (int k = 0; k < 8; ++k) v[k] = (bf16_t)0.f;
        }
#pragma unroll
        for (int k = 0; k < 8; ++k) Bs[pp + jj * 8 + k][c] = v[k];
      }
    }
    __syncthreads();
#pragma unroll
    for (int ks = 0; ks < 2; ++ks) {
      const bf16x8 af = *(const bf16x8*)&As[w * 16 + l15][ks * 32 + g * 8];
#pragma unroll
      for (int n = 0; n < 4; ++n) {
        const bf16x8 bfr = *(const bf16x8*)&Bs[n * 16 + l15][ks * 32 + g * 8];
        acc[n] = mfma16(af, bfr, acc[n]);
      }
    }
    __syncthreads();
  }

  if (blockIdx.y < 6) {
    const int h = blockIdx.y;
#pragma unroll
    for (int n = 0; n < 4; ++n) {
      const int l = p0 + n * 16 + l15;
      if (l < P) {
        bf16x4 kq;
#pragma unroll
        for (int r = 0; r < 4; ++r) kq[r] = (bf16_t)acc[n][r];
        *(bf16x4*)&ktb[(((size_t)b * NHEAD + h) * LKV + l) * DHEAD + w * 16 + g * 4] = kq;
      }
    }
  } else {
#pragma unroll
    for (int n = 0; n < 4; ++n) {
      const int p = p0 + n * 16 + l15;
      if (p < P) {
#pragma unroll
        for (int r = 0; r < 4; ++r) {
          const int c = o0 - DIMX + w * 16 + g * 4 + r;
          vtb[((size_t)b * DIMX + c) * LKV + p] = (bf16_t)acc[n][r];
        }
      }
    }
  }
}

// ---------------------------------------------------------------------------
// Depthwise 5x5 stride-2 conv + bias + BN + exact GELU.
// Zero-padded 60x60 LDS plane -> branch-free 25-tap conv.
// ---------------------------------------------------------------------------
__global__ __launch_bounds__(256) void dw_bn_gelu(
    const bf16_t* __restrict__ q, const float* __restrict__ dw_w,
    const float* __restrict__ dw_b, const float* __restrict__ bn_w,
    const float* __restrict__ bn_b, const float* __restrict__ bn_mean,
    const float* __restrict__ bn_var, float* __restrict__ off)
{
  __shared__ float pl[3600];   // 60x60 padded plane
  const int nc = blockIdx.x;
  const int c  = nc & 127;
  const bf16_t* plane = q + (size_t)nc * HW;
  const int tid = threadIdx.x;

  for (int i = tid; i < 3600; i += 256) pl[i] = 0.f;
  float w[25];
#pragma unroll
  for (int k = 0; k < 25; ++k) w[k] = dw_w[c * 25 + k];
  const float beta  = dw_b[c];
  const float scale = bn_w[c] * rsqrtf(bn_var[c] + 1e-6f);
  const float shift = bn_b[c] - bn_mean[c] * scale;
  __syncthreads();

  for (int i = tid; i < 392; i += 256) {
    const bf16x8 v = *(const bf16x8*)(plane + i * 8);
    const int y = i / 7, x0 = (i % 7) * 8;
    float* dst = &pl[(y + 2) * 60 + 2 + x0];
#pragma unroll
    for (int k = 0; k < 8; ++k) dst[k] = (float)v[k];
  }
  __syncthreads();

  for (int p = tid; p < LKV; p += 256) {
    const int oy = p / 28, ox = p % 28;
    float s = 0.f;
#pragma unroll
    for (int ky = 0; ky < 5; ++ky)
#pragma unroll
      for (int kx = 0; kx < 5; ++kx)
        s += pl[(oy * 2 + ky) * 60 + ox * 2 + kx] * w[ky * 5 + kx];
    s = (s + beta) * scale + shift;
    const float g = 0.5f * s * (1.f + erff(s * 0.70710678118654752f));
    off[(size_t)nc * LKV + p] = g;
  }
}

// ---------------------------------------------------------------------------
// Pointwise (3,128) -> offsets / double-sigmoid modulation -> sample coords.
// 64-thread blocks: 16 p-lanes x 4 c-slices, shfl reduce. grid (49, 24).
// ---------------------------------------------------------------------------
__global__ __launch_bounds__(64) void om_grid(
    const float* __restrict__ off, const float* __restrict__ pw_w,
    float* __restrict__ gxy, float* __restrict__ modb)
{
  const int n  = blockIdx.y;
  const int lane = threadIdx.x;
  const int p  = blockIdx.x * 16 + (lane & 15);
  const int cs = lane >> 4;
  const float* base = off + (size_t)n * NGDX * LKV + p;
  float s0 = 0.f, s1 = 0.f, s2 = 0.f;
#pragma unroll 8
  for (int cc = 0; cc < 32; ++cc) {
    const int c = cs * 32 + cc;
    const float v = base[(size_t)c * LKV];
    s0 += v * pw_w[c];
    s1 += v * pw_w[128 + c];
    s2 += v * pw_w[256 + c];
  }
  s0 += __shfl_xor(s0, 16); s0 += __shfl_xor(s0, 32);
  s1 += __shfl_xor(s1, 16); s1 += __shfl_xor(s1, 32);
  s2 += __shfl_xor(s2, 16); s2 += __shfl_xor(s2, 32);
  if (cs == 0) {
    const float sig1 = 1.f / (1.f + expf(-s2));
    const float mod  = 1.f / (1.f + expf(-sig1));   // double sigmoid (per reference)
    const float offy = tanhf(s0) * (2.f / 28.f);
    const float offx = tanhf(s1) * (2.f / 28.f);
    const int i = p / 28, j = p % 28;
    const float refy = ((i + 0.5f) / 28.f) * 2.f - 1.f;
    const float refx = ((j + 0.5f) / 28.f) * 2.f - 1.f;
    const float gy = (offy + refy + 1.f) * 0.5f * 55.f;
    const float gx = (offx + refx + 1.f) * 0.5f * 55.f;
    gxy[((size_t)n * LKV + p) * 2 + 0] = gx;
    gxy[((size_t)n * LKV + p) * 2 + 1] = gy;
    modb[(size_t)n * LKV + p] = mod;
  }
}

// ---------------------------------------------------------------------------
// Bilinear sample * modulation -> bf16 (c-major, feeds kv GEMM scatter path)
// ---------------------------------------------------------------------------
__global__ __launch_bounds__(256) void sample_mod(
    const float* __restrict__ x, const float* __restrict__ gxy,
    const float* __restrict__ modb, bf16_t* __restrict__ xs)
{
  const int nc = blockIdx.x;
  const int n  = nc >> 7;
  const float* img = x + (size_t)nc * HW;
  for (int p = threadIdx.x; p < LKV; p += 256) {
    const float gx = gxy[((size_t)n * LKV + p) * 2 + 0];
    const float gy = gxy[((size_t)n * LKV + p) * 2 + 1];
    const float x0f = floorf(gx), y0f = floorf(gy);
    const float wx1 = gx - x0f, wy1 = gy - y0f;
    const float wx0 = (x0f + 1.f) - gx, wy0 = (y0f + 1.f) - gy;
    const int ix0 = (int)x0f, iy0 = (int)y0f;
    const int ix1 = ix0 + 1,  iy1 = iy0 + 1;
    const bool vx0 = (ix0 >= 0) && (ix0 < 56), vx1 = (ix1 >= 0) && (ix1 < 56);
    const bool vy0 = (iy0 >= 0) && (iy0 < 56), vy1 = (iy1 >= 0) && (iy1 < 56);
    const int cx0 = min(max(ix0, 0), 55), cx1 = min(max(ix1, 0), 55);
    const int cy0 = min(max(iy0, 0), 55), cy1 = min(max(iy1, 0), 55);
    const float f00 = (vy0 && vx0) ? img[cy0 * 56 + cx0] : 0.f;
    const float f10 = (vy1 && vx0) ? img[cy1 * 56 + cx0] : 0.f;
    const float f01 = (vy0 && vx1) ? img[cy0 * 56 + cx1] : 0.f;
    const float f11 = (vy1 && vx1) ? img[cy1 * 56 + cx1] : 0.f;
    const float v = f00 * (wx0 * wy0) + f10 * (wx0 * wy1)
                  + f01 * (wx1 * wy0) + f11 * (wx1 * wy1);
    xs[(size_t)nc * LKV + p] = (bf16_t)(v * modb[(size_t)n * LKV + p]);
  }
}

// ---------------------------------------------------------------------------
// bf16 MFMA attention (R12 config — best measured): 4 waves, Q-tile 128,
// swapped QK^T, no-max softmax, double-buffered K/V, ones-MFMA lsum,
// per-rs fused P-write+PV, grid 1200 = 25 p-tiles x 48 bh (XCD-grouped).
// LDS (40KB): K0 0 | V0 8K | K1 16K | V1 24K | Pt 32K..40K
// ---------------------------------------------------------------------------
__global__ __launch_bounds__(256, 3) void attn_mfma(
    const bf16_t* __restrict__ q, const bf16_t* __restrict__ kt,
    const bf16_t* __restrict__ vt, bf16_t* __restrict__ aot)
{
  const int blk = blockIdx.x;
  const int bh  = blk % 48;       // same-XCD group (48 % 8 == 0)
  const int t25 = blk / 48;
  const int h   = bh % NHEAD;
  const int b   = bh / NHEAD;
  const int p0  = t25 * 128;

  __shared__ __align__(16) char smem[40960];
  float (*Os)[68] = (float (*)[68])(smem);          // epilogue reuse

  const int tid  = threadIdx.x;
  const int w    = tid >> 6;
  const int lane = tid & 63;
  const int l15  = lane & 15;
  const int g    = lane >> 4;
  const int lrow = lane >> 3;   // 0..7
  const int j    = lane & 7;

  const bf16_t* qb = q  + (size_t)(b * DIMX + h * DHEAD) * HW;
  const bf16_t* kb = kt + ((size_t)(b * NHEAD + h) * LKV) * DHEAD;
  const bf16_t* vb = vt + (size_t)(b * DIMX + h * DHEAD) * LKV;

  const bf16_t* gK = kb + (size_t)(w * 16 + lrow) * DHEAD + (j ^ lrow) * 8;
  const bf16_t* gV = vb + (size_t)(w * 16 + lrow) * LKV + (j ^ lrow) * 8;

  const float QSCL = 0.18033688011112042f;
  bf16x8 qf[2][2];
#pragma unroll
  for (int rs = 0; rs < 2; ++rs) {
    const int p = p0 + w * 32 + rs * 16 + l15;
    const bool valid = p < HW;
#pragma unroll
    for (int c2 = 0; c2 < 2; ++c2)
#pragma unroll
      for (int i = 0; i < 8; ++i) {
        const int d = c2 * 32 + g * 8 + i;
        qf[rs][c2][i] = valid ? (bf16_t)((float)qb[(size_t)d * HW + p] * QSCL) : (bf16_t)0.f;
      }
  }
  bf16x8 ones;
#pragma unroll
  for (int i = 0; i < 8; ++i) ones[i] = (bf16_t)1.0f;

  f32x4 acc[2][4];
  f32x4 lacc[2];
#pragma unroll
  for (int rs = 0; rs < 2; ++rs) {
    lacc[rs][0]=0.f; lacc[rs][1]=0.f; lacc[rs][2]=0.f; lacc[rs][3]=0.f;
#pragma unroll
    for (int n = 0; n < 4; ++n) { acc[rs][n][0]=0.f; acc[rs][n][1]=0.f; acc[rs][n][2]=0.f; acc[rs][n][3]=0.f; }
  }

  gload16(gK,                    smem + w * 2048);
  gload16(gK + (size_t)8*DHEAD,  smem + w * 2048 + 1024);
  gload16(gV,                    smem + 8192 + w * 2048);
  gload16(gV + (size_t)8*LKV,    smem + 8192 + w * 2048 + 1024);

  for (int t = 0; t < 13; ++t) {
    const int l0  = t * 64;
    const int buf = (t & 1) * 16384;
    __syncthreads();
    if (t < 12) {
      const int l1 = t * 64 + 64;
      const int nb = ((t + 1) & 1) * 16384;
      gload16(gK + (size_t)l1 * DHEAD,       smem + nb + w * 2048);
      gload16(gK + (size_t)(l1 + 8) * DHEAD, smem + nb + w * 2048 + 1024);
      gload16(gV + l1,                       smem + nb + 8192 + w * 2048);
      gload16(gV + (size_t)8 * LKV + l1,     smem + nb + 8192 + w * 2048 + 1024);
    }

    f32x4 s[2][4];
    __builtin_amdgcn_s_setprio(1);
#pragma unroll
    for (int n = 0; n < 4; ++n) {
      const int row = n * 16 + l15;
      const int cx0 = (g * 16) ^ ((l15 & 7) << 4);
      const int cx1 = (64 + g * 16) ^ ((l15 & 7) << 4);
      const bf16x8 k0 = *(const bf16x8*)(smem + buf + row * 128 + cx0);
      const bf16x8 k1 = *(const bf16x8*)(smem + buf + row * 128 + cx1);
#pragma unroll
      for (int rs = 0; rs < 2; ++rs) {
        f32x4 z; z[0]=0.f; z[1]=0.f; z[2]=0.f; z[3]=0.f;
        z = mfma16(k0, qf[rs][0], z);
        z = mfma16(k1, qf[rs][1], z);
        s[rs][n] = z;
      }
    }
    __builtin_amdgcn_s_setprio(0);
    if (l0 + 64 > LKV) {
#pragma unroll
      for (int n = 0; n < 4; ++n)
#pragma unroll
        for (int r = 0; r < 4; ++r)
          if (l0 + n * 16 + g * 4 + r >= LKV) {
#pragma unroll
            for (int rs = 0; rs < 2; ++rs) s[rs][n][r] = -1e30f;
          }
    }

    const int prow  = w * 16 + l15;
    char* pbase = smem + 32768 + prow * 128;
#pragma unroll
    for (int rs = 0; rs < 2; ++rs) {
#pragma unroll
      for (int n = 0; n < 4; ++n) {
        bf16x4 pk;
#pragma unroll
        for (int r = 0; r < 4; ++r) pk[r] = (bf16_t)exp2f(s[rs][n][r]);
        *(bf16x4*)(pbase + ((n * 32 + g * 8) ^ ((l15 & 7) << 4))) = pk;
      }
      __builtin_amdgcn_s_setprio(1);
#pragma unroll
      for (int c2 = 0; c2 < 2; ++c2) {
        bf16x8 vf[4];
#pragma unroll
        for (int n = 0; n < 4; ++n) {
          const int row = n * 16 + l15;
          const int cx = (c2 * 64 + g * 16) ^ ((l15 & 7) << 4);
          vf[n] = *(const bf16x8*)(smem + 8192 + buf + row * 128 + cx);
        }
        const bf16x8 pf = *(const bf16x8*)(pbase + ((c2 * 64 + g * 16) ^ ((l15 & 7) << 4)));
        lacc[rs] = mfma16(ones, pf, lacc[rs]);
#pragma unroll
        for (int n = 0; n < 4; ++n)
          acc[rs][n] = mfma16(vf[n], pf, acc[rs][n]);
      }
      __builtin_amdgcn_s_setprio(0);
    }
  }
  __syncthreads();

#pragma unroll
  for (int rs = 0; rs < 2; ++rs) {
    const float inv = 1.f / lacc[rs][0];
#pragma unroll
    for (int n = 0; n < 4; ++n) {
      f32x4 o4;
#pragma unroll
      for (int r = 0; r < 4; ++r) o4[r] = acc[rs][n][r] * inv;
      *(f32x4*)&Os[w * 32 + rs * 16 + l15][n * 16 + g * 4] = o4;
    }
  }
  __syncthreads();
  {
    const int pr = tid >> 1, c0 = (tid & 1) * 32;
    const int p = p0 + pr;
    if (p < HW) {
      bf16_t* dst = aot + ((size_t)b * HW + p) * DIMX + h * DHEAD + c0;
#pragma unroll
      for (int jj = 0; jj < 4; ++jj) {
        const f32x4 a = *(const f32x4*)&Os[pr][c0 + jj * 8];
        const f32x4 bq = *(const f32x4*)&Os[pr][c0 + jj * 8 + 4];
        bf16x8 o8;
        o8[0]=(bf16_t)a[0]; o8[1]=(bf16_t)a[1]; o8[2]=(bf16_t)a[2]; o8[3]=(bf16_t)a[3];
        o8[4]=(bf16_t)bq[0]; o8[5]=(bf16_t)bq[1]; o8[6]=(bf16_t)bq[2]; o8[7]=(bf16_t)bq[3];
        *(bf16x8*)(dst + jj * 8) = o8;
      }
    }
  }
}

// ---------------------------------------------------------------------------
extern "C" void kernel_launch(void* const* d_in, const int* in_sizes, int n_in,
                              void* d_out, int out_size, void* d_ws, size_t ws_size,
                              hipStream_t stream) {
  const float* x       = (const float*)d_in[0];
  const float* q_w     = (const float*)d_in[1];
  const float* kv_w    = (const float*)d_in[2];
  const float* proj_w  = (const float*)d_in[3];
  const float* proj_b  = (const float*)d_in[4];
  const float* dw_w    = (const float*)d_in[5];
  const float* dw_b    = (const float*)d_in[6];
  const float* bn_w    = (const float*)d_in[7];
  const float* bn_b    = (const float*)d_in[8];
  const float* bn_mean = (const float*)d_in[9];
  const float* bn_var  = (const float*)d_in[10];
  const float* pw_w    = (const float*)d_in[11];
  float* out = (float*)d_out;

  // workspace (bytes), total ~68.8 MB
  char* ws = (char*)d_ws;
  bf16_t* qbufb = (bf16_t*)(ws);                      // 19,267,584 (8,384,3136) bf16
  float*  offb  = (float*)(ws + 19267584);            //  9,633,792 (24,128,784) f32
  float*  gxy   = (float*)(ws + 28901376);            //    150,528
  float*  modb  = (float*)(ws + 29051904);            //     75,264
  bf16_t* ktb   = (bf16_t*)(ws + 29127168);           //  4,816,896 (8,6,784,64) bf16
  bf16_t* vtb   = (bf16_t*)(ws + 33944064);           //  4,816,896 (8,384,784) bf16
  bf16_t* xsb   = (bf16_t*)(ws + 38760960);           //  4,816,896 (24,128,784) bf16
  bf16_t* aot   = (bf16_t*)(ws + 43577856);           // 19,267,584 (8,3136,384) bf16
  bf16_t* wbf   = (bf16_t*)(ws + 62845440);           //  1,179,648 weights bf16
  bf16_t* q_wb  = wbf;
  bf16_t* kv_wb = wbf + 147456;
  bf16_t* pj_wb = wbf + 442368;

  const dim3 blk(256);
  // 0. weight converts
  cvt_w3<<<dim3(576), blk, 0, stream>>>(q_w, kv_w, proj_w, wbf);
  // 1. q projection (fused x fp32 read, bf16 out)
  gemm_q<<<dim3(2352), blk, 0, stream>>>(q_wb, x, qbufb);
  // 2. depthwise conv + BN + GELU (bf16 in, padded-plane branch-free)
  dw_bn_gelu<<<dim3(3072), blk, 0, stream>>>(qbufb, dw_w, dw_b, bn_w, bn_b, bn_mean, bn_var, offb);
  // 3. pointwise -> offsets + (double-sigmoid) modulation -> coords
  om_grid<<<dim3(49, 24), dim3(64), 0, stream>>>(offb, pw_w, gxy, modb);
  // 4. bilinear sample * modulation -> bf16 (c-major)
  sample_mod<<<dim3(3072), blk, 0, stream>>>(x, gxy, modb, xsb);
  // 5. kv projection -> K transposed [b,h,l,d] + V [b,c,l]
  gemm_kv<<<dim3(13, 12, 8), blk, 0, stream>>>(kv_wb, xsb, ktb, vtb, 384, 784, 768);
  // 6. attention (R12 config: 4-wave Q128, XCD-grouped) -> aot (b,p,c) bf16
  attn_mfma<<<dim3(1200), blk, 0, stream>>>(qbufb, ktb, vtb, aot);
  // 7. out projection (+bias, dbuf fast path + XCD swizzle) -> d_out fp32
  gemm_qo<<<dim3(2352), blk, 0, stream>>>(pj_wb, aot, proj_b, out, 384, 3136, 384);
}

// Round 15
// 156.823 us; speedup vs baseline: 1.0520x; 1.0520x over previous
//
#include <hip/hip_runtime.h>
#include <math.h>

#define DIMX 384
#define NHEAD 6
#define DHEAD 64
#define HW 3136   // 56*56
#define LKV 784   // 28*28
#define NGDX 128
#define NGRP 24   // B*3

typedef __bf16 bf16_t;
typedef __bf16 bf16x4 __attribute__((ext_vector_type(4)));
typedef __bf16 bf16x8 __attribute__((ext_vector_type(8)));
typedef float  f32x4  __attribute__((ext_vector_type(4)));

typedef unsigned int u32_g __attribute__((address_space(1)));
typedef unsigned int u32_l __attribute__((address_space(3)));

static __device__ __forceinline__ f32x4 mfma16(bf16x8 a, bf16x8 b, f32x4 c) {
  return __builtin_amdgcn_mfma_f32_16x16x32_bf16(a, b, c, 0, 0, 0);
}
// async global->LDS, 16B per lane; LDS dest = wave-uniform base + lane*16
static __device__ __forceinline__ void gload16(const void* g, void* l) {
  __builtin_amdgcn_global_load_lds((const u32_g*)g, (u32_l*)l, 16, 0, 0);
}

// ---------------------------------------------------------------------------
// x (b,c,p) fp32 -> xt (b,p,c) bf16, LDS 64x64 tile transpose
// ---------------------------------------------------------------------------
__global__ __launch_bounds__(256) void xt_cvt(
    const float* __restrict__ x, bf16_t* __restrict__ xt)
{
  const int p0 = blockIdx.x * 64, c0 = blockIdx.y * 64, b = blockIdx.z;
  __shared__ float T[64][65];
  const int tid = threadIdx.x;
  {
    const int c = tid >> 2, pc = (tid & 3) * 16;
    const float* src = x + ((size_t)b * DIMX + c0 + c) * HW + p0 + pc;
#pragma unroll
    for (int j = 0; j < 4; ++j) {
      const float4 v = *(const float4*)(src + j * 4);
      T[c][pc + j * 4 + 0] = v.x; T[c][pc + j * 4 + 1] = v.y;
      T[c][pc + j * 4 + 2] = v.z; T[c][pc + j * 4 + 3] = v.w;
    }
  }
  __syncthreads();
  {
    const int p = tid >> 2, cc = (tid & 3) * 16;
    bf16_t* dst = xt + ((size_t)b * HW + p0 + p) * DIMX + c0 + cc;
#pragma unroll
    for (int jj = 0; jj < 2; ++jj) {
      bf16x8 o;
#pragma unroll
      for (int k = 0; k < 8; ++k) o[k] = (bf16_t)T[cc + jj * 8 + k][p];
      *(bf16x8*)(dst + jj * 8) = o;
    }
  }
}

// convert the three weight matrices into one bf16 arena
__global__ __launch_bounds__(256) void cvt_w3(
    const float* __restrict__ qw, const float* __restrict__ kvw,
    const float* __restrict__ pw, bf16_t* __restrict__ dst)
{
  const int i = blockIdx.x * 256 + threadIdx.x;
  if (i >= 147456) return;
  const int e = i * 4;
  const float* src;
  int off;
  if (e < 147456)      { src = qw;  off = e; }
  else if (e < 442368) { src = kvw; off = e - 147456; }
  else                 { src = pw;  off = e - 442368; }
  const float4 v = *(const float4*)(src + off);
  bf16x4 o;
  o[0] = (bf16_t)v.x; o[1] = (bf16_t)v.y; o[2] = (bf16_t)v.z; o[3] = (bf16_t)v.w;
  *(bf16x4*)(dst + e) = o;
}

// ---------------------------------------------------------------------------
// Fast GEMM for q-proj / out-proj. Double-buffered global_load_lds staging,
// 1 barrier per K-step; XOR-swizzled reads. 1-D grid 2352 with XCD-locality
// mapping: blk = y*392 + (b*49 + x).
// ---------------------------------------------------------------------------
template<bool BIAS, bool OBF16>
__global__ __launch_bounds__(256) void gemm_qo(
    const bf16_t* __restrict__ W, const bf16_t* __restrict__ in,
    const float* __restrict__ bias, void* __restrict__ outv,
    int C, int P, int O)
{
  const int blk = blockIdx.x;
  const int y   = blk / 392;
  const int xb  = blk % 392;
  const int b   = xb / 49;
  const int o0  = y * 64;
  const int p0  = (xb % 49) * 64;
  __shared__ __align__(16) char smem[32768];
  const int tid = threadIdx.x;
  const int w = tid >> 6, lane = tid & 63, l15 = lane & 15, g = lane >> 4;
  const int lrow = lane >> 3;
  const int j    = lane & 7;

  const bf16_t* gA = W + (size_t)(o0 + w * 16 + lrow) * C + (j ^ lrow) * 8;
  const bf16_t* gB = in + ((size_t)b * P + p0 + w * 16 + lrow) * C + (j ^ lrow) * 8;

  f32x4 acc[4];
#pragma unroll
  for (int n = 0; n < 4; ++n) { acc[n][0]=0.f; acc[n][1]=0.f; acc[n][2]=0.f; acc[n][3]=0.f; }

  gload16(gA,         smem + w * 2048);
  gload16(gA + 8 * C, smem + w * 2048 + 1024);
  gload16(gB,         smem + 8192 + w * 2048);
  gload16(gB + 8 * C, smem + 8192 + w * 2048 + 1024);

  const int NK = C >> 6;
  for (int it = 0; it < NK; ++it) {
    const int buf = (it & 1) * 16384;
    __syncthreads();
    if (it + 1 < NK) {
      const int c1 = (it + 1) * 64;
      const int nb = ((it + 1) & 1) * 16384;
      gload16(gA + c1,         smem + nb + w * 2048);
      gload16(gA + c1 + 8 * C, smem + nb + w * 2048 + 1024);
      gload16(gB + c1,         smem + nb + 8192 + w * 2048);
      gload16(gB + c1 + 8 * C, smem + nb + 8192 + w * 2048 + 1024);
    }
#pragma unroll
    for (int ks = 0; ks < 2; ++ks) {
      const int cx = (ks * 64 + g * 16) ^ ((l15 & 7) << 4);
      const bf16x8 af = *(const bf16x8*)(smem + buf + (w * 16 + l15) * 128 + cx);
#pragma unroll
      for (int n = 0; n < 4; ++n) {
        const bf16x8 bfr = *(const bf16x8*)(smem + buf + 8192 + (n * 16 + l15) * 128 + cx);
        acc[n] = mfma16(af, bfr, acc[n]);
      }
    }
  }

  float badd[4];
#pragma unroll
  for (int r = 0; r < 4; ++r) badd[r] = BIAS ? bias[o0 + w * 16 + g * 4 + r] : 0.f;
#pragma unroll
  for (int n = 0; n < 4; ++n) {
    const int p = p0 + n * 16 + l15;
#pragma unroll
    for (int r = 0; r < 4; ++r) {
      const int o = o0 + w * 16 + g * 4 + r;
      const float v = acc[n][r] + badd[r];
      if (OBF16) ((bf16_t*)outv)[((size_t)b * O + o) * P + p] = (bf16_t)v;
      else       ((float*)outv)[((size_t)b * O + o) * P + p] = v;
    }
  }
}

// ---------------------------------------------------------------------------
// bf16 MFMA GEMM (kv projection): in (b,c,p) transpose-scatter staging.
// Epilogue: o<384 -> K transposed [b,h,l,d]; o>=384 -> V [b,c,l].
// ---------------------------------------------------------------------------
__global__ __launch_bounds__(256) void gemm_kv(
    const bf16_t* __restrict__ W, const bf16_t* __restrict__ in,
    bf16_t* __restrict__ ktb, bf16_t* __restrict__ vtb, int C, int P, int O)
{
  const int b  = blockIdx.z;
  const int o0 = blockIdx.y * 64;
  const int p0 = blockIdx.x * 64;
  __shared__ __align__(16) bf16_t As[64][72];
  __shared__ __align__(16) bf16_t Bs[64][72];
  const int tid = threadIdx.x;
  const int w = tid >> 6, lane = tid & 63, l15 = lane & 15, g = lane >> 4;

  f32x4 acc[4];
#pragma unroll
  for (int n = 0; n < 4; ++n) { acc[n][0]=0.f; acc[n][1]=0.f; acc[n][2]=0.f; acc[n][3]=0.f; }

  for (int c0 = 0; c0 < C; c0 += 64) {
    {
      const int o = tid >> 2, cc = (tid & 3) * 16;
      const bf16_t* src = W + (size_t)(o0 + o) * C + c0 + cc;
      *(bf16x8*)&As[o][cc]     = *(const bf16x8*)src;
      *(bf16x8*)&As[o][cc + 8] = *(const bf16x8*)(src + 8);
    }
    {
      const int c = tid >> 2, pp = (tid & 3) * 16;
      const bf16_t* src = in + ((size_t)b * C + c0 + c) * P + p0 + pp;
#pragma unroll
      for (int jj = 0; jj < 2; ++jj) {
        bf16x8 v;
        if (p0 + pp + jj * 8 + 8 <= P) v = *(const bf16x8*)(src + jj * 8);
        else {
#pragma unroll
          for (int k = 0; k < 8; ++k) v[k] = (bf16_t)0.f;
        }
#pragma unroll
        for (int k = 0; k < 8; ++k) Bs[pp + jj * 8 + k][c] = v[k];
      }
    }
    __syncthreads();
#pragma unroll
    for (int ks = 0; ks < 2; ++ks) {
      const bf16x8 af = *(const bf16x8*)&As[w * 16 + l15][ks * 32 + g * 8];
#pragma unroll
      for (int n = 0; n < 4; ++n) {
        const bf16x8 bfr = *(const bf16x8*)&Bs[n * 16 + l15][ks * 32 + g * 8];
        acc[n] = mfma16(af, bfr, acc[n]);
      }
    }
    __syncthreads();
  }

  if (blockIdx.y < 6) {
    const int h = blockIdx.y;
#pragma unroll
    for (int n = 0; n < 4; ++n) {
      const int l = p0 + n * 16 + l15;
      if (l < P) {
        bf16x4 kq;
#pragma unroll
        for (int r = 0; r < 4; ++r) kq[r] = (bf16_t)acc[n][r];
        *(bf16x4*)&ktb[(((size_t)b * NHEAD + h) * LKV + l) * DHEAD + w * 16 + g * 4] = kq;
      }
    }
  } else {
#pragma unroll
    for (int n = 0; n < 4; ++n) {
      const int p = p0 + n * 16 + l15;
      if (p < P) {
#pragma unroll
        for (int r = 0; r < 4; ++r) {
          const int c = o0 - DIMX + w * 16 + g * 4 + r;
          vtb[((size_t)b * DIMX + c) * LKV + p] = (bf16_t)acc[n][r];
        }
      }
    }
  }
}

// ---------------------------------------------------------------------------
// Depthwise 5x5 stride-2 conv + bias + BN + exact GELU.
// Zero-padded 60x60 LDS plane -> branch-free 25-tap conv. Output bf16.
// ---------------------------------------------------------------------------
__global__ __launch_bounds__(256) void dw_bn_gelu(
    const bf16_t* __restrict__ q, const float* __restrict__ dw_w,
    const float* __restrict__ dw_b, const float* __restrict__ bn_w,
    const float* __restrict__ bn_b, const float* __restrict__ bn_mean,
    const float* __restrict__ bn_var, bf16_t* __restrict__ off)
{
  __shared__ float pl[3600];   // 60x60 padded plane
  const int nc = blockIdx.x;
  const int c  = nc & 127;
  const bf16_t* plane = q + (size_t)nc * HW;
  const int tid = threadIdx.x;

  for (int i = tid; i < 3600; i += 256) pl[i] = 0.f;
  float w[25];
#pragma unroll
  for (int k = 0; k < 25; ++k) w[k] = dw_w[c * 25 + k];
  const float beta  = dw_b[c];
  const float scale = bn_w[c] * rsqrtf(bn_var[c] + 1e-6f);
  const float shift = bn_b[c] - bn_mean[c] * scale;
  __syncthreads();

  for (int i = tid; i < 392; i += 256) {
    const bf16x8 v = *(const bf16x8*)(plane + i * 8);
    const int y = i / 7, x0 = (i % 7) * 8;
    float* dst = &pl[(y + 2) * 60 + 2 + x0];
#pragma unroll
    for (int k = 0; k < 8; ++k) dst[k] = (float)v[k];
  }
  __syncthreads();

  for (int p = tid; p < LKV; p += 256) {
    const int oy = p / 28, ox = p % 28;
    float s = 0.f;
#pragma unroll
    for (int ky = 0; ky < 5; ++ky)
#pragma unroll
      for (int kx = 0; kx < 5; ++kx)
        s += pl[(oy * 2 + ky) * 60 + ox * 2 + kx] * w[ky * 5 + kx];
    s = (s + beta) * scale + shift;
    const float g = 0.5f * s * (1.f + erff(s * 0.70710678118654752f));
    off[(size_t)nc * LKV + p] = (bf16_t)g;
  }
}

// ---------------------------------------------------------------------------
// Pointwise (3,128) -> offsets / double-sigmoid modulation -> sample coords.
// 64-thread blocks: 16 p-lanes x 4 c-slices, shfl reduce. grid (49, 24).
// offb is bf16.
// ---------------------------------------------------------------------------
__global__ __launch_bounds__(64) void om_grid(
    const bf16_t* __restrict__ off, const float* __restrict__ pw_w,
    float* __restrict__ gxy, float* __restrict__ modb)
{
  const int n  = blockIdx.y;
  const int lane = threadIdx.x;
  const int p  = blockIdx.x * 16 + (lane & 15);
  const int cs = lane >> 4;
  const bf16_t* base = off + (size_t)n * NGDX * LKV + p;
  float s0 = 0.f, s1 = 0.f, s2 = 0.f;
#pragma unroll 8
  for (int cc = 0; cc < 32; ++cc) {
    const int c = cs * 32 + cc;
    const float v = (float)base[(size_t)c * LKV];
    s0 += v * pw_w[c];
    s1 += v * pw_w[128 + c];
    s2 += v * pw_w[256 + c];
  }
  s0 += __shfl_xor(s0, 16); s0 += __shfl_xor(s0, 32);
  s1 += __shfl_xor(s1, 16); s1 += __shfl_xor(s1, 32);
  s2 += __shfl_xor(s2, 16); s2 += __shfl_xor(s2, 32);
  if (cs == 0) {
    const float sig1 = 1.f / (1.f + expf(-s2));
    const float mod  = 1.f / (1.f + expf(-sig1));   // double sigmoid (per reference)
    const float offy = tanhf(s0) * (2.f / 28.f);
    const float offx = tanhf(s1) * (2.f / 28.f);
    const int i = p / 28, j = p % 28;
    const float refy = ((i + 0.5f) / 28.f) * 2.f - 1.f;
    const float refx = ((j + 0.5f) / 28.f) * 2.f - 1.f;
    const float gy = (offy + refy + 1.f) * 0.5f * 55.f;
    const float gx = (offx + refx + 1.f) * 0.5f * 55.f;
    gxy[((size_t)n * LKV + p) * 2 + 0] = gx;
    gxy[((size_t)n * LKV + p) * 2 + 1] = gy;
    modb[(size_t)n * LKV + p] = mod;
  }
}

// ---------------------------------------------------------------------------
// Bilinear sample * modulation -> bf16 (c-major, feeds kv GEMM scatter path)
// ---------------------------------------------------------------------------
__global__ __launch_bounds__(256) void sample_mod(
    const float* __restrict__ x, const float* __restrict__ gxy,
    const float* __restrict__ modb, bf16_t* __restrict__ xs)
{
  const int nc = blockIdx.x;
  const int n  = nc >> 7;
  const float* img = x + (size_t)nc * HW;
  for (int p = threadIdx.x; p < LKV; p += 256) {
    const float gx = gxy[((size_t)n * LKV + p) * 2 + 0];
    const float gy = gxy[((size_t)n * LKV + p) * 2 + 1];
    const float x0f = floorf(gx), y0f = floorf(gy);
    const float wx1 = gx - x0f, wy1 = gy - y0f;
    const float wx0 = (x0f + 1.f) - gx, wy0 = (y0f + 1.f) - gy;
    const int ix0 = (int)x0f, iy0 = (int)y0f;
    const int ix1 = ix0 + 1,  iy1 = iy0 + 1;
    const bool vx0 = (ix0 >= 0) && (ix0 < 56), vx1 = (ix1 >= 0) && (ix1 < 56);
    const bool vy0 = (iy0 >= 0) && (iy0 < 56), vy1 = (iy1 >= 0) && (iy1 < 56);
    const int cx0 = min(max(ix0, 0), 55), cx1 = min(max(ix1, 0), 55);
    const int cy0 = min(max(iy0, 0), 55), cy1 = min(max(iy1, 0), 55);
    const float f00 = (vy0 && vx0) ? img[cy0 * 56 + cx0] : 0.f;
    const float f10 = (vy1 && vx0) ? img[cy1 * 56 + cx0] : 0.f;
    const float f01 = (vy0 && vx1) ? img[cy0 * 56 + cx1] : 0.f;
    const float f11 = (vy1 && vx1) ? img[cy1 * 56 + cx1] : 0.f;
    const float v = f00 * (wx0 * wy0) + f10 * (wx0 * wy1)
                  + f01 * (wx1 * wy0) + f11 * (wx1 * wy1);
    xs[(size_t)nc * LKV + p] = (bf16_t)(v * modb[(size_t)n * LKV + p]);
  }
}

// ---------------------------------------------------------------------------
// bf16 MFMA attention (R12 config — best measured): 4 waves, Q-tile 128,
// swapped QK^T, no-max softmax, double-buffered K/V, ones-MFMA lsum,
// per-rs fused P-write+PV, grid 1200 = 25 p-tiles x 48 bh (XCD-grouped).
// LDS (40KB): K0 0 | V0 8K | K1 16K | V1 24K | Pt 32K..40K
// ---------------------------------------------------------------------------
__global__ __launch_bounds__(256, 3) void attn_mfma(
    const bf16_t* __restrict__ q, const bf16_t* __restrict__ kt,
    const bf16_t* __restrict__ vt, bf16_t* __restrict__ aot)
{
  const int blk = blockIdx.x;
  const int bh  = blk % 48;       // same-XCD group (48 % 8 == 0)
  const int t25 = blk / 48;
  const int h   = bh % NHEAD;
  const int b   = bh / NHEAD;
  const int p0  = t25 * 128;

  __shared__ __align__(16) char smem[40960];
  float (*Os)[68] = (float (*)[68])(smem);          // epilogue reuse

  const int tid  = threadIdx.x;
  const int w    = tid >> 6;
  const int lane = tid & 63;
  const int l15  = lane & 15;
  const int g    = lane >> 4;
  const int lrow = lane >> 3;   // 0..7
  const int j    = lane & 7;

  const bf16_t* qb = q  + (size_t)(b * DIMX + h * DHEAD) * HW;
  const bf16_t* kb = kt + ((size_t)(b * NHEAD + h) * LKV) * DHEAD;
  const bf16_t* vb = vt + (size_t)(b * DIMX + h * DHEAD) * LKV;

  const bf16_t* gK = kb + (size_t)(w * 16 + lrow) * DHEAD + (j ^ lrow) * 8;
  const bf16_t* gV = vb + (size_t)(w * 16 + lrow) * LKV + (j ^ lrow) * 8;

  const float QSCL = 0.18033688011112042f;
  bf16x8 qf[2][2];
#pragma unroll
  for (int rs = 0; rs < 2; ++rs) {
    const int p = p0 + w * 32 + rs * 16 + l15;
    const bool valid = p < HW;
#pragma unroll
    for (int c2 = 0; c2 < 2; ++c2)
#pragma unroll
      for (int i = 0; i < 8; ++i) {
        const int d = c2 * 32 + g * 8 + i;
        qf[rs][c2][i] = valid ? (bf16_t)((float)qb[(size_t)d * HW + p] * QSCL) : (bf16_t)0.f;
      }
  }
  bf16x8 ones;
#pragma unroll
  for (int i = 0; i < 8; ++i) ones[i] = (bf16_t)1.0f;

  f32x4 acc[2][4];
  f32x4 lacc[2];
#pragma unroll
  for (int rs = 0; rs < 2; ++rs) {
    lacc[rs][0]=0.f; lacc[rs][1]=0.f; lacc[rs][2]=0.f; lacc[rs][3]=0.f;
#pragma unroll
    for (int n = 0; n < 4; ++n) { acc[rs][n][0]=0.f; acc[rs][n][1]=0.f; acc[rs][n][2]=0.f; acc[rs][n][3]=0.f; }
  }

  gload16(gK,                    smem + w * 2048);
  gload16(gK + (size_t)8*DHEAD,  smem + w * 2048 + 1024);
  gload16(gV,                    smem + 8192 + w * 2048);
  gload16(gV + (size_t)8*LKV,    smem + 8192 + w * 2048 + 1024);

  for (int t = 0; t < 13; ++t) {
    const int l0  = t * 64;
    const int buf = (t & 1) * 16384;
    __syncthreads();
    if (t < 12) {
      const int l1 = t * 64 + 64;
      const int nb = ((t + 1) & 1) * 16384;
      gload16(gK + (size_t)l1 * DHEAD,       smem + nb + w * 2048);
      gload16(gK + (size_t)(l1 + 8) * DHEAD, smem + nb + w * 2048 + 1024);
      gload16(gV + l1,                       smem + nb + 8192 + w * 2048);
      gload16(gV + (size_t)8 * LKV + l1,     smem + nb + 8192 + w * 2048 + 1024);
    }

    f32x4 s[2][4];
    __builtin_amdgcn_s_setprio(1);
#pragma unroll
    for (int n = 0; n < 4; ++n) {
      const int row = n * 16 + l15;
      const int cx0 = (g * 16) ^ ((l15 & 7) << 4);
      const int cx1 = (64 + g * 16) ^ ((l15 & 7) << 4);
      const bf16x8 k0 = *(const bf16x8*)(smem + buf + row * 128 + cx0);
      const bf16x8 k1 = *(const bf16x8*)(smem + buf + row * 128 + cx1);
#pragma unroll
      for (int rs = 0; rs < 2; ++rs) {
        f32x4 z; z[0]=0.f; z[1]=0.f; z[2]=0.f; z[3]=0.f;
        z = mfma16(k0, qf[rs][0], z);
        z = mfma16(k1, qf[rs][1], z);
        s[rs][n] = z;
      }
    }
    __builtin_amdgcn_s_setprio(0);
    if (l0 + 64 > LKV) {
#pragma unroll
      for (int n = 0; n < 4; ++n)
#pragma unroll
        for (int r = 0; r < 4; ++r)
          if (l0 + n * 16 + g * 4 + r >= LKV) {
#pragma unroll
            for (int rs = 0; rs < 2; ++rs) s[rs][n][r] = -1e30f;
          }
    }

    const int prow  = w * 16 + l15;
    char* pbase = smem + 32768 + prow * 128;
#pragma unroll
    for (int rs = 0; rs < 2; ++rs) {
#pragma unroll
      for (int n = 0; n < 4; ++n) {
        bf16x4 pk;
#pragma unroll
        for (int r = 0; r < 4; ++r) pk[r] = (bf16_t)exp2f(s[rs][n][r]);
        *(bf16x4*)(pbase + ((n * 32 + g * 8) ^ ((l15 & 7) << 4))) = pk;
      }
      __builtin_amdgcn_s_setprio(1);
#pragma unroll
      for (int c2 = 0; c2 < 2; ++c2) {
        bf16x8 vf[4];
#pragma unroll
        for (int n = 0; n < 4; ++n) {
          const int row = n * 16 + l15;
          const int cx = (c2 * 64 + g * 16) ^ ((l15 & 7) << 4);
          vf[n] = *(const bf16x8*)(smem + 8192 + buf + row * 128 + cx);
        }
        const bf16x8 pf = *(const bf16x8*)(pbase + ((c2 * 64 + g * 16) ^ ((l15 & 7) << 4)));
        lacc[rs] = mfma16(ones, pf, lacc[rs]);
#pragma unroll
        for (int n = 0; n < 4; ++n)
          acc[rs][n] = mfma16(vf[n], pf, acc[rs][n]);
      }
      __builtin_amdgcn_s_setprio(0);
    }
  }
  __syncthreads();

#pragma unroll
  for (int rs = 0; rs < 2; ++rs) {
    const float inv = 1.f / lacc[rs][0];
#pragma unroll
    for (int n = 0; n < 4; ++n) {
      f32x4 o4;
#pragma unroll
      for (int r = 0; r < 4; ++r) o4[r] = acc[rs][n][r] * inv;
      *(f32x4*)&Os[w * 32 + rs * 16 + l15][n * 16 + g * 4] = o4;
    }
  }
  __syncthreads();
  {
    const int pr = tid >> 1, c0 = (tid & 1) * 32;
    const int p = p0 + pr;
    if (p < HW) {
      bf16_t* dst = aot + ((size_t)b * HW + p) * DIMX + h * DHEAD + c0;
#pragma unroll
      for (int jj = 0; jj < 4; ++jj) {
        const f32x4 a = *(const f32x4*)&Os[pr][c0 + jj * 8];
        const f32x4 bq = *(const f32x4*)&Os[pr][c0 + jj * 8 + 4];
        bf16x8 o8;
        o8[0]=(bf16_t)a[0]; o8[1]=(bf16_t)a[1]; o8[2]=(bf16_t)a[2]; o8[3]=(bf16_t)a[3];
        o8[4]=(bf16_t)bq[0]; o8[5]=(bf16_t)bq[1]; o8[6]=(bf16_t)bq[2]; o8[7]=(bf16_t)bq[3];
        *(bf16x8*)(dst + jj * 8) = o8;
      }
    }
  }
}

// ---------------------------------------------------------------------------
extern "C" void kernel_launch(void* const* d_in, const int* in_sizes, int n_in,
                              void* d_out, int out_size, void* d_ws, size_t ws_size,
                              hipStream_t stream) {
  const float* x       = (const float*)d_in[0];
  const float* q_w     = (const float*)d_in[1];
  const float* kv_w    = (const float*)d_in[2];
  const float* proj_w  = (const float*)d_in[3];
  const float* proj_b  = (const float*)d_in[4];
  const float* dw_w    = (const float*)d_in[5];
  const float* dw_b    = (const float*)d_in[6];
  const float* bn_w    = (const float*)d_in[7];
  const float* bn_b    = (const float*)d_in[8];
  const float* bn_mean = (const float*)d_in[9];
  const float* bn_var  = (const float*)d_in[10];
  const float* pw_w    = (const float*)d_in[11];
  float* out = (float*)d_out;

  // workspace (bytes), total ~64 MB
  char* ws = (char*)d_ws;
  bf16_t* qbufb = (bf16_t*)(ws);                      // 19,267,584 (8,384,3136) bf16
  bf16_t* offb  = (bf16_t*)(ws + 19267584);           //  4,816,896 (24,128,784) bf16
  float*  gxy   = (float*)(ws + 24084480);            //    150,528
  float*  modb  = (float*)(ws + 24235008);            //     75,264
  bf16_t* ktb   = (bf16_t*)(ws + 24310272);           //  4,816,896 (8,6,784,64) bf16
  bf16_t* vtb   = (bf16_t*)(ws + 29127168);           //  4,816,896 (8,384,784) bf16
  bf16_t* xsb   = (bf16_t*)(ws + 33944064);           //  4,816,896 (24,128,784) bf16
  bf16_t* xt    = (bf16_t*)(ws + 38760960);           // 19,267,584 (8,3136,384) bf16
  bf16_t* aot   = xt;                                 // overlay: xt dead after q-proj
  bf16_t* wbf   = (bf16_t*)(ws + 58028544);           //  1,179,648 weights bf16
  bf16_t* q_wb  = wbf;
  bf16_t* kv_wb = wbf + 147456;
  bf16_t* pj_wb = wbf + 442368;

  const dim3 blk(256);
  // 0. converts
  xt_cvt<<<dim3(49, 6, 8), blk, 0, stream>>>(x, xt);
  cvt_w3<<<dim3(576), blk, 0, stream>>>(q_w, kv_w, proj_w, wbf);
  // 1. q projection (dbuf fast path + XCD swizzle, bf16 out)
  gemm_qo<false, true><<<dim3(2352), blk, 0, stream>>>(q_wb, xt, nullptr, qbufb, 384, 3136, 384);
  // 2. depthwise conv + BN + GELU (bf16 in/out, padded-plane branch-free)
  dw_bn_gelu<<<dim3(3072), blk, 0, stream>>>(qbufb, dw_w, dw_b, bn_w, bn_b, bn_mean, bn_var, offb);
  // 3. pointwise -> offsets + (double-sigmoid) modulation -> coords
  om_grid<<<dim3(49, 24), dim3(64), 0, stream>>>(offb, pw_w, gxy, modb);
  // 4. bilinear sample * modulation -> bf16 (c-major)
  sample_mod<<<dim3(3072), blk, 0, stream>>>(x, gxy, modb, xsb);
  // 5. kv projection -> K transposed [b,h,l,d] + V [b,c,l]
  gemm_kv<<<dim3(13, 12, 8), blk, 0, stream>>>(kv_wb, xsb, ktb, vtb, 384, 784, 768);
  // 6. attention (R12 config: 4-wave Q128, XCD-grouped) -> aot (b,p,c) bf16
  attn_mfma<<<dim3(1200), blk, 0, stream>>>(qbufb, ktb, vtb, aot);
  // 7. out projection (+bias, dbuf fast path + XCD swizzle) -> d_out fp32
  gemm_qo<true, false><<<dim3(2352), blk, 0, stream>>>(pj_wb, aot, proj_b, out, 384, 3136, 384);
}